// Round 7
// baseline (289.957 us; speedup 1.0000x reference)
//
#include <hip/hip_runtime.h>
#include <hip/hip_bf16.h>

typedef unsigned short u16;
typedef __bf16 bf16x8 __attribute__((ext_vector_type(8)));
typedef __bf16 bf16x4 __attribute__((ext_vector_type(4)));
typedef unsigned int u32x4 __attribute__((ext_vector_type(4)));
typedef float f32x4 __attribute__((ext_vector_type(4)));

#define SEQ 2048
#define DMODEL 512
#define NHEAD 8
#define DFF 2048
#define NBATCH 8
#define MROWS (NBATCH * SEQ)

// 0.125 * log2(e): folded into w_q/b_q so attn softmax is exp2(s) directly
#define C1_FOLD 0.18033688f

__device__ __forceinline__ u16 f2b(float f) {
    __hip_bfloat16 h = __float2bfloat16(f);
    u16 u;
    __builtin_memcpy(&u, &h, 2);
    return u;
}

__device__ __forceinline__ unsigned int pack2(float a, float b) {
    float2 f{a, b};
    __hip_bfloat162 h = __float22bfloat162_rn(f);
    unsigned int u;
    __builtin_memcpy(&u, &h, 4);
    return u;
}

__device__ __forceinline__ float ex2(float x) {
#if __has_builtin(__builtin_amdgcn_exp2f)
    return __builtin_amdgcn_exp2f(x);
#else
    return exp2f(x);
#endif
}

// async global->LDS, 16B per lane. LDS dest must be wave-uniform base; lane i
// lands at base + i*16.
__device__ __forceinline__ void gload_lds16(const void* g, void* lds) {
    auto* gp = reinterpret_cast<const __attribute__((address_space(1))) unsigned int*>(
        reinterpret_cast<uintptr_t>(g));
    auto* lp = reinterpret_cast<__attribute__((address_space(3))) unsigned int*>(
        reinterpret_cast<uintptr_t>(lds));
    __builtin_amdgcn_global_load_lds(gp, lp, 16, 0, 0);
}

// ---------------------------------------------------------------------------
// Weight cast fp32 -> bf16 (6 matrices in one launch). w_q scaled by C1.
// ---------------------------------------------------------------------------
__global__ __launch_bounds__(256) void cast_weights(
    const float* __restrict__ w0, const float* __restrict__ w1,
    const float* __restrict__ w2, const float* __restrict__ w3,
    const float* __restrict__ w4, const float* __restrict__ w5,
    u16* __restrict__ d0, u16* __restrict__ d1, u16* __restrict__ d2,
    u16* __restrict__ d3, u16* __restrict__ d4, u16* __restrict__ d5) {
    int blk = blockIdx.x;
    const float* s;
    u16* d;
    int base;
    float sc = 1.0f;
    if (blk < 512) {
        int seg = blk >> 7, lb = blk & 127;
        s = seg == 0 ? w0 : seg == 1 ? w1 : seg == 2 ? w2 : w3;
        d = seg == 0 ? d0 : seg == 1 ? d1 : seg == 2 ? d2 : d3;
        base = lb * 2048;
        if (seg == 0) sc = C1_FOLD;
    } else if (blk < 1024) {
        s = w4; d = d4; base = (blk - 512) * 2048;
    } else {
        s = w5; d = d5; base = (blk - 1024) * 2048;
    }
    int i = base + threadIdx.x * 8;
    float4 a = *reinterpret_cast<const float4*>(s + i);
    float4 b = *reinterpret_cast<const float4*>(s + i + 4);
    ushort4 oa, ob;
    oa.x = f2b(a.x * sc); oa.y = f2b(a.y * sc);
    oa.z = f2b(a.z * sc); oa.w = f2b(a.w * sc);
    ob.x = f2b(b.x * sc); ob.y = f2b(b.y * sc);
    ob.z = f2b(b.z * sc); ob.w = f2b(b.w * sc);
    *reinterpret_cast<ushort4*>(d + i) = oa;
    *reinterpret_cast<ushort4*>(d + i + 4) = ob;
}

// concat b_q*C1 | b_k | b_v -> bqkv[1536]
__global__ __launch_bounds__(256) void concat_bias(const float* __restrict__ bq,
                                                   const float* __restrict__ bk,
                                                   const float* __restrict__ bv,
                                                   float* __restrict__ dst) {
    int i = blockIdx.x * 256 + threadIdx.x;
    float v = i < 512 ? bq[i] * C1_FOLD : (i < 1024 ? bk[i - 512] : bv[i - 1024]);
    dst[i] = v;
}

// ---------------------------------------------------------------------------
// LayerNorm (unbiased var, ddof=1), fp32 in -> bf16 out. 1 wave / 512-row.
// ---------------------------------------------------------------------------
__global__ __launch_bounds__(256) void ln_rows(const float* __restrict__ x,
                                               u16* __restrict__ out) {
    int row = blockIdx.x * 4 + (threadIdx.x >> 6);
    int l = threadIdx.x & 63;
    const float* xr = x + (size_t)row * DMODEL + l * 8;
    float4 a = *reinterpret_cast<const float4*>(xr);
    float4 b = *reinterpret_cast<const float4*>(xr + 4);
    float s = a.x + a.y + a.z + a.w + b.x + b.y + b.z + b.w;
    float q = a.x * a.x + a.y * a.y + a.z * a.z + a.w * a.w +
              b.x * b.x + b.y * b.y + b.z * b.z + b.w * b.w;
#pragma unroll
    for (int d = 32; d >= 1; d >>= 1) {
        s += __shfl_xor(s, d, 64);
        q += __shfl_xor(q, d, 64);
    }
    float mean = s * (1.f / 512.f);
    float var = (q - 512.f * mean * mean) * (1.f / 511.f);
    float rs = rsqrtf(var + 1e-6f);
    ushort4 o0, o1;
    o0.x = f2b((a.x - mean) * rs); o0.y = f2b((a.y - mean) * rs);
    o0.z = f2b((a.z - mean) * rs); o0.w = f2b((a.w - mean) * rs);
    o1.x = f2b((b.x - mean) * rs); o1.y = f2b((b.y - mean) * rs);
    o1.z = f2b((b.z - mean) * rs); o1.w = f2b((b.w - mean) * rs);
    u16* op = out + (size_t)row * DMODEL + l * 8;
    *reinterpret_cast<ushort4*>(op) = o0;
    *reinterpret_cast<ushort4*>(op + 4) = o1;
}

// ---------------------------------------------------------------------------
// GEMM: C[M,N] = A[M,K] @ W[N,K]^T
// OUTMODE: 0 = bf16 row-major, 1 = fp32 row-major,
//          3 = fused QKV: cols <1024 -> qk buffer [M][1024]; cols >=1024 ->
//              V4 interleaved store (B, S/4, 512, 4) (block-uniform on n0).
// ---------------------------------------------------------------------------
template <bool RELU, bool RESID, int OUTMODE>
__global__ __launch_bounds__(256, 2) void gemm_nt(
    const u16* __restrict__ A, const u16* __restrict__ W,
    const float* __restrict__ bias, const float* __restrict__ resid,
    void* __restrict__ Cout, void* __restrict__ Cout2, int N, int K) {
    __shared__ u16 Als[128 * 64];
    __shared__ u16 Bls[128 * 64];
    const int tid = threadIdx.x;
    const int l = tid & 63, w = tid >> 6;
    const int m0 = blockIdx.y * 128;
    const int n0 = blockIdx.x * 128;
    const int wr = (w >> 1) * 64, wc = (w & 1) * 64;
    const int lhi = l >> 4, l15 = l & 15, l7 = l & 7;

    f32x4 acc[4][4] = {};

    const int srow = l >> 3;
    const int scol = ((l & 7) * 8) ^ (srow << 3);

    for (int kt = 0; kt < K; kt += 64) {
        __syncthreads();
#pragma unroll
        for (int i = 0; i < 4; ++i) {
            int cc = w * 4 + i;
            int grow = cc * 8 + srow;
            gload_lds16(&A[(size_t)(m0 + grow) * K + kt + scol], &Als[cc * 512]);
            gload_lds16(&W[(size_t)(n0 + grow) * K + kt + scol], &Bls[cc * 512]);
        }
        __syncthreads();
#pragma unroll
        for (int kk = 0; kk < 2; ++kk) {
            const int koff = (kk * 32 + lhi * 8) ^ (l7 << 3);
            bf16x8 af[4], bfr[4];
#pragma unroll
            for (int m = 0; m < 4; ++m)
                af[m] = *reinterpret_cast<const bf16x8*>(
                    &Als[(wr + m * 16 + l15) * 64 + koff]);
#pragma unroll
            for (int n = 0; n < 4; ++n)
                bfr[n] = *reinterpret_cast<const bf16x8*>(
                    &Bls[(wc + n * 16 + l15) * 64 + koff]);
#pragma unroll
            for (int m = 0; m < 4; ++m)
#pragma unroll
                for (int n = 0; n < 4; ++n)
                    acc[m][n] = __builtin_amdgcn_mfma_f32_16x16x32_bf16(
                        af[m], bfr[n], acc[m][n], 0, 0, 0);
        }
    }

    int colg[4];
    float bv[4];
#pragma unroll
    for (int cn = 0; cn < 4; ++cn) {
        colg[cn] = n0 + wc + cn * 16 + l15;
        bv[cn] = bias[colg[cn]];
    }
#pragma unroll
    for (int am = 0; am < 4; ++am) {
        int rowg = m0 + wr + am * 16 + 4 * lhi;
#pragma unroll
        for (int cn = 0; cn < 4; ++cn) {
            float v[4];
#pragma unroll
            for (int r = 0; r < 4; ++r) {
                float t = acc[am][cn][r] + bv[cn];
                if constexpr (RELU) t = fmaxf(t, 0.f);
                if constexpr (RESID)
                    t += resid[(size_t)(rowg + r) * N + colg[cn]];
                v[r] = t;
            }
            if constexpr (OUTMODE == 0) {
                u16* o = (u16*)Cout;
#pragma unroll
                for (int r = 0; r < 4; ++r)
                    o[(size_t)(rowg + r) * N + colg[cn]] = f2b(v[r]);
            } else if constexpr (OUTMODE == 1) {
                float* o = (float*)Cout;
#pragma unroll
                for (int r = 0; r < 4; ++r)
                    o[(size_t)(rowg + r) * N + colg[cn]] = v[r];
            } else {
                // fused QKV: n0 is block-uniform
                if (n0 < 1024) {
                    u16* o = (u16*)Cout;  // qk buffer [M][1024]
#pragma unroll
                    for (int r = 0; r < 4; ++r)
                        o[(size_t)(rowg + r) * 1024 + colg[cn]] = f2b(v[r]);
                } else {
                    // V4: (B, S/4, 512, 4): elem = b*1048576 + (s>>2)*2048
                    //                              + d*4 + (s&3)
                    u16* o = (u16*)Cout2;
                    int bb = rowg >> 11, sloc = rowg & 2047;  // sloc % 4 == 0
                    int dg = colg[cn] - 1024;
                    ushort4 pk;
                    pk.x = f2b(v[0]); pk.y = f2b(v[1]);
                    pk.z = f2b(v[2]); pk.w = f2b(v[3]);
                    *reinterpret_cast<ushort4*>(
                        &o[(size_t)bb * 1048576 + (size_t)(sloc >> 2) * 2048 +
                           dg * 4]) = pk;
                }
            }
        }
    }
}

// ---------------------------------------------------------------------------
// Flash attention v7: K LDS (source-swizzled) + V4 LDS (conflict-free by
// layout), swapped QK^T (C1 pre-folded into w_q), clamped no-max softmax,
// PV at 16x16x32 with slot-matched key pairing. Double-buffered, t-loop
// unrolled x2 so buf is compile-time (LDS addrs -> base + imm offsets).
// qk: (B,S,1024) bf16; v4: (B,S/4,512,4) bf16.
// Block = 128 q x (b,h), 4 waves; grid 1024 (XCD-swizzled), 4 blocks/CU.
// ---------------------------------------------------------------------------
__global__ __launch_bounds__(256, 4) void attn_fwd(
    const u16* __restrict__ qk, const u16* __restrict__ v4,
    const int* __restrict__ mask, u16* __restrict__ out) {
    __shared__ u16 Kls[2][64 * 64];
    __shared__ u16 Vls[2][64 * 64];  // [kg 0..15][d 0..63][key&3]
    const int tid = threadIdx.x;
    const int l = tid & 63, w = tid >> 6;
    const int lhi = l >> 4, l15 = l & 15;
    const int lb = (blockIdx.x & 7) * 128 + (blockIdx.x >> 3);  // XCD swizzle
    const int qt = lb & 15, bh = lb >> 4;
    const int b = bh >> 3, h = bh & 7;
    const int q0 = qt * 128 + w * 32;

    const u16* Qb = qk + (size_t)b * SEQ * 1024 + h * 64;
    const u16* Kb = Qb + 512;
    const u16* Vb4 = v4 + (size_t)b * 1048576 + h * 256;
    const int* Mb = mask + b * SEQ;

    const int srow = l >> 3;
    const int scol = ((l & 7) ^ srow) << 3;  // source-swizzled 16B chunk (K)

    bf16x8 qf[2][2];
#pragma unroll
    for (int g = 0; g < 2; ++g) {
        size_t qa = (size_t)(q0 + g * 16 + l15) * 1024 + lhi * 8;
        qf[g][0] = *reinterpret_cast<const bf16x8*>(&Qb[qa]);
        qf[g][1] = *reinterpret_cast<const bf16x8*>(&Qb[qa + 32]);
    }

    // whole-sequence mask check, once per block (fallback path kept general)
    int allone;
    {
        int acc = 1;
#pragma unroll
        for (int i = 0; i < 8; ++i) {
            int4 mm = *reinterpret_cast<const int4*>(&Mb[l * 32 + i * 4]);
            acc &= mm.x & mm.y & mm.z & mm.w;
        }
        allone = __all(acc == 1);
    }

    float lrun[2] = {0.f, 0.f};
    f32x4 oacc[2][4] = {};

    auto stage = [&](int buf, int kv) {
#pragma unroll
        for (int i = 0; i < 2; ++i) {
            int cc = w * 2 + i;
            int row = cc * 8 + srow;
            gload_lds16(&Kb[(size_t)(kv + row) * 1024 + scol], &Kls[buf][cc * 512]);
            gload_lds16(&Vb4[(size_t)((kv >> 2) + cc * 2 + (l >> 5)) * 2048 +
                             (l & 31) * 8],
                        &Vls[buf][cc * 512]);
        }
    };

    const int sw = (l15 & 7) << 3;

    // one KV tile: buf and pf are compile-time at each call site
    auto tile = [&](int buf, int kv, bool pf, int pbuf, int pkv) {
        if (pf) stage(pbuf, pkv);
        __builtin_amdgcn_sched_barrier(0);

        // --- QK^T (swapped): sc[g][ks][r] = S[key=kv+ks*16+4lhi+r][q=l15+16g]
        f32x4 sc[2][4];
        __builtin_amdgcn_s_setprio(1);
#pragma unroll
        for (int ks = 0; ks < 4; ++ks) {
            int krow = ks * 16 + l15;
            bf16x8 ka0 = *reinterpret_cast<const bf16x8*>(
                &Kls[buf][krow * 64 + ((lhi * 8) ^ sw)]);
            bf16x8 ka1 = *reinterpret_cast<const bf16x8*>(
                &Kls[buf][krow * 64 + ((32 + lhi * 8) ^ sw)]);
#pragma unroll
            for (int g = 0; g < 2; ++g) {
                f32x4 z = {};
                z = __builtin_amdgcn_mfma_f32_16x16x32_bf16(ka0, qf[g][0], z, 0, 0, 0);
                z = __builtin_amdgcn_mfma_f32_16x16x32_bf16(ka1, qf[g][1], z, 0, 0, 0);
                sc[g][ks] = z;
            }
        }
        __builtin_amdgcn_s_setprio(0);

        if (!allone) {
            int4 mm[4];
#pragma unroll
            for (int ks = 0; ks < 4; ++ks)
                mm[ks] = *reinterpret_cast<const int4*>(&Mb[kv + ks * 16 + 4 * lhi]);
#pragma unroll
            for (int ks = 0; ks < 4; ++ks) {
                if (mm[ks].x == 0) { sc[0][ks][0] = -3e38f; sc[1][ks][0] = -3e38f; }
                if (mm[ks].y == 0) { sc[0][ks][1] = -3e38f; sc[1][ks][1] = -3e38f; }
                if (mm[ks].z == 0) { sc[0][ks][2] = -3e38f; sc[1][ks][2] = -3e38f; }
                if (mm[ks].w == 0) { sc[0][ks][3] = -3e38f; sc[1][ks][3] = -3e38f; }
            }
        }

        // --- clamped no-max softmax: p = exp2(min(s, 30)) (C1 pre-folded).
        u32x4 pku[2][2];
#pragma unroll
        for (int g = 0; g < 2; ++g) {
            float ps = 0.f;
#pragma unroll
            for (int ks = 0; ks < 4; ++ks) {
                float p0 = ex2(fminf(sc[g][ks][0], 30.f));
                float p1 = ex2(fminf(sc[g][ks][1], 30.f));
                float p2 = ex2(fminf(sc[g][ks][2], 30.f));
                float p3 = ex2(fminf(sc[g][ks][3], 30.f));
                ps += (p0 + p1) + (p2 + p3);
                pku[g][ks >> 1][(ks & 1) * 2 + 0] = pack2(p0, p1);
                pku[g][ks >> 1][(ks & 1) * 2 + 1] = pack2(p2, p3);
            }
            ps += __shfl_xor(ps, 16, 64);
            ps += __shfl_xor(ps, 32, 64);
            lrun[g] += ps;
        }

        // --- PV at 16x16x32: slot j<4 -> key kp*32+4lhi+j; j>=4 -> +16.
        __builtin_amdgcn_s_setprio(1);
#pragma unroll
        for (int kp = 0; kp < 2; ++kp) {
#pragma unroll
            for (int dc = 0; dc < 4; ++dc) {
                int dl4 = (dc * 16 + l15) * 4;
                bf16x4 v0 = *reinterpret_cast<const bf16x4*>(
                    &Vls[buf][(kp * 8 + lhi) * 256 + dl4]);
                bf16x4 v1 = *reinterpret_cast<const bf16x4*>(
                    &Vls[buf][(kp * 8 + 4 + lhi) * 256 + dl4]);
                bf16x8 vb8;
                vb8[0] = v0[0]; vb8[1] = v0[1]; vb8[2] = v0[2]; vb8[3] = v0[3];
                vb8[4] = v1[0]; vb8[5] = v1[1]; vb8[6] = v1[2]; vb8[7] = v1[3];
#pragma unroll
                for (int g = 0; g < 2; ++g)
                    oacc[g][dc] = __builtin_amdgcn_mfma_f32_16x16x32_bf16(
                        __builtin_bit_cast(bf16x8, pku[g][kp]), vb8, oacc[g][dc],
                        0, 0, 0);
            }
        }
        __builtin_amdgcn_s_setprio(0);

        asm volatile("s_waitcnt vmcnt(0)" ::: "memory");
        __builtin_amdgcn_s_barrier();
    };

    stage(0, 0);
    asm volatile("s_waitcnt vmcnt(0)" ::: "memory");
    __builtin_amdgcn_s_barrier();

    for (int tt = 0; tt < 16; ++tt) {
        const int base = tt * 128;
        tile(0, base, true, 1, base + 64);
        tile(1, base + 64, tt < 15, 0, base + 128);
    }

    // --- epilogue: oacc row = q = 4lhi+r, col d = 16dc+l15
#pragma unroll
    for (int g = 0; g < 2; ++g) {
        float inv = 1.f / lrun[g];
        float invr[4];
#pragma unroll
        for (int r = 0; r < 4; ++r) invr[r] = __shfl(inv, 4 * lhi + r, 16);
#pragma unroll
        for (int r = 0; r < 4; ++r) {
            size_t rowa =
                ((size_t)b * SEQ + q0 + g * 16 + 4 * lhi + r) * DMODEL + h * 64;
#pragma unroll
            for (int dc = 0; dc < 4; ++dc)
                out[rowa + dc * 16 + l15] = f2b(oacc[g][dc][r] * invr[r]);
        }
    }
}

// ---------------------------------------------------------------------------
extern "C" void kernel_launch(void* const* d_in, const int* in_sizes, int n_in,
                              void* d_out, int out_size, void* d_ws,
                              size_t ws_size, hipStream_t stream) {
    const float* x = (const float*)d_in[0];
    const int* mask = (const int*)d_in[1];
    const float* w_q = (const float*)d_in[2];
    const float* b_q = (const float*)d_in[3];
    const float* w_k = (const float*)d_in[4];
    const float* b_k = (const float*)d_in[5];
    const float* w_v = (const float*)d_in[6];
    const float* b_v = (const float*)d_in[7];
    const float* w_o = (const float*)d_in[8];
    const float* b_o = (const float*)d_in[9];
    const float* w_1 = (const float*)d_in[10];
    const float* b_1 = (const float*)d_in[11];
    const float* w_2 = (const float*)d_in[12];
    const float* b_2 = (const float*)d_in[13];

    char* ws = (char*)d_ws;
    const size_t MB = 1024ull * 1024ull;
    u16* lnx = (u16*)(ws + 0);          // 16 MiB; reused as attn_out
    u16* qkb = (u16*)(ws + 16 * MB);    // 32 MiB [16,48): q|k interleaved rows
    u16* v4 = (u16*)(ws + 48 * MB);     // 16 MiB [48,64): (B,S/4,512,4)
    u16* lnx1 = (u16*)(ws + 16 * MB);   // after attn, qkb dead
    u16* hbuf = (u16*)(ws + 32 * MB);   // 64 MiB [32,96); qkb-hi, v4 dead
    u16* wqkv = (u16*)(ws + 96 * MB);   // [1536][512] (q|k|v rows contiguous)
    u16* wob = wqkv + 3 * 262144;
    u16* w1b = wqkv + 4 * 262144;
    u16* w2b = w1b + 1048576;
    float* bqkv = (float*)(w2b + 1048576);  // 1536 floats
    u16* attn_o = lnx;
    float* x1 = (float*)d_out;

    cast_weights<<<1536, 256, 0, stream>>>(
        w_q, w_k, w_v, w_o, w_1, w_2, wqkv, wqkv + 262144, wqkv + 2 * 262144,
        wob, w1b, w2b);
    concat_bias<<<6, 256, 0, stream>>>(b_q, b_k, b_v, bqkv);
    ln_rows<<<4096, 256, 0, stream>>>(x, lnx);

    dim3 g12(12, 128), g4(4, 128), g16(16, 128);
    gemm_nt<false, false, 3><<<g12, 256, 0, stream>>>(lnx, wqkv, bqkv, nullptr,
                                                      qkb, v4, 1536, 512);
    attn_fwd<<<1024, 256, 0, stream>>>(qkb, v4, mask, attn_o);
    gemm_nt<false, true, 1><<<g4, 256, 0, stream>>>(attn_o, wob, b_o, x, x1,
                                                    nullptr, 512, 512);
    ln_rows<<<4096, 256, 0, stream>>>(x1, lnx1);
    gemm_nt<true, false, 0><<<g16, 256, 0, stream>>>(lnx1, w1b, b_1, nullptr,
                                                     hbuf, nullptr, 2048, 512);
    gemm_nt<false, true, 1><<<g4, 256, 0, stream>>>(hbuf, w2b, b_2, x1,
                                                    (float*)d_out, nullptr,
                                                    512, 2048);
}

// Round 8
// 282.545 us; speedup vs baseline: 1.0262x; 1.0262x over previous
//
#include <hip/hip_runtime.h>
#include <hip/hip_bf16.h>

typedef unsigned short u16;
typedef __bf16 bf16x8 __attribute__((ext_vector_type(8)));
typedef __bf16 bf16x4 __attribute__((ext_vector_type(4)));
typedef unsigned int u32x4 __attribute__((ext_vector_type(4)));
typedef float f32x4 __attribute__((ext_vector_type(4)));

#define SEQ 2048
#define DMODEL 512
#define NHEAD 8
#define DFF 2048
#define NBATCH 8
#define MROWS (NBATCH * SEQ)

// 0.125 * log2(e): folded into w_q/b_q so attn softmax is exp2(s) directly
#define C1_FOLD 0.18033688f

__device__ __forceinline__ u16 f2b(float f) {
    __hip_bfloat16 h = __float2bfloat16(f);
    u16 u;
    __builtin_memcpy(&u, &h, 2);
    return u;
}

__device__ __forceinline__ unsigned int pack2(float a, float b) {
    float2 f{a, b};
    __hip_bfloat162 h = __float22bfloat162_rn(f);
    unsigned int u;
    __builtin_memcpy(&u, &h, 4);
    return u;
}

__device__ __forceinline__ float ex2(float x) {
#if __has_builtin(__builtin_amdgcn_exp2f)
    return __builtin_amdgcn_exp2f(x);
#else
    return exp2f(x);
#endif
}

// async global->LDS, 16B per lane. LDS dest must be wave-uniform base; lane i
// lands at base + i*16.
__device__ __forceinline__ void gload_lds16(const void* g, void* lds) {
    auto* gp = reinterpret_cast<const __attribute__((address_space(1))) unsigned int*>(
        reinterpret_cast<uintptr_t>(g));
    auto* lp = reinterpret_cast<__attribute__((address_space(3))) unsigned int*>(
        reinterpret_cast<uintptr_t>(lds));
    __builtin_amdgcn_global_load_lds(gp, lp, 16, 0, 0);
}

// ---------------------------------------------------------------------------
// Weight cast fp32 -> bf16 (6 matrices in one launch). w_q scaled by C1.
// ---------------------------------------------------------------------------
__global__ __launch_bounds__(256) void cast_weights(
    const float* __restrict__ w0, const float* __restrict__ w1,
    const float* __restrict__ w2, const float* __restrict__ w3,
    const float* __restrict__ w4, const float* __restrict__ w5,
    u16* __restrict__ d0, u16* __restrict__ d1, u16* __restrict__ d2,
    u16* __restrict__ d3, u16* __restrict__ d4, u16* __restrict__ d5) {
    int blk = blockIdx.x;
    const float* s;
    u16* d;
    int base;
    float sc = 1.0f;
    if (blk < 512) {
        int seg = blk >> 7, lb = blk & 127;
        s = seg == 0 ? w0 : seg == 1 ? w1 : seg == 2 ? w2 : w3;
        d = seg == 0 ? d0 : seg == 1 ? d1 : seg == 2 ? d2 : d3;
        base = lb * 2048;
        if (seg == 0) sc = C1_FOLD;
    } else if (blk < 1024) {
        s = w4; d = d4; base = (blk - 512) * 2048;
    } else {
        s = w5; d = d5; base = (blk - 1024) * 2048;
    }
    int i = base + threadIdx.x * 8;
    float4 a = *reinterpret_cast<const float4*>(s + i);
    float4 b = *reinterpret_cast<const float4*>(s + i + 4);
    ushort4 oa, ob;
    oa.x = f2b(a.x * sc); oa.y = f2b(a.y * sc);
    oa.z = f2b(a.z * sc); oa.w = f2b(a.w * sc);
    ob.x = f2b(b.x * sc); ob.y = f2b(b.y * sc);
    ob.z = f2b(b.z * sc); ob.w = f2b(b.w * sc);
    *reinterpret_cast<ushort4*>(d + i) = oa;
    *reinterpret_cast<ushort4*>(d + i + 4) = ob;
}

// concat b_q*C1 | b_k | b_v -> bqkv[1536]
__global__ __launch_bounds__(256) void concat_bias(const float* __restrict__ bq,
                                                   const float* __restrict__ bk,
                                                   const float* __restrict__ bv,
                                                   float* __restrict__ dst) {
    int i = blockIdx.x * 256 + threadIdx.x;
    float v = i < 512 ? bq[i] * C1_FOLD : (i < 1024 ? bk[i - 512] : bv[i - 1024]);
    dst[i] = v;
}

// ---------------------------------------------------------------------------
// LayerNorm (unbiased var, ddof=1), fp32 in -> bf16 out. 1 wave / 512-row.
// ---------------------------------------------------------------------------
__global__ __launch_bounds__(256) void ln_rows(const float* __restrict__ x,
                                               u16* __restrict__ out) {
    int row = blockIdx.x * 4 + (threadIdx.x >> 6);
    int l = threadIdx.x & 63;
    const float* xr = x + (size_t)row * DMODEL + l * 8;
    float4 a = *reinterpret_cast<const float4*>(xr);
    float4 b = *reinterpret_cast<const float4*>(xr + 4);
    float s = a.x + a.y + a.z + a.w + b.x + b.y + b.z + b.w;
    float q = a.x * a.x + a.y * a.y + a.z * a.z + a.w * a.w +
              b.x * b.x + b.y * b.y + b.z * b.z + b.w * b.w;
#pragma unroll
    for (int d = 32; d >= 1; d >>= 1) {
        s += __shfl_xor(s, d, 64);
        q += __shfl_xor(q, d, 64);
    }
    float mean = s * (1.f / 512.f);
    float var = (q - 512.f * mean * mean) * (1.f / 511.f);
    float rs = rsqrtf(var + 1e-6f);
    ushort4 o0, o1;
    o0.x = f2b((a.x - mean) * rs); o0.y = f2b((a.y - mean) * rs);
    o0.z = f2b((a.z - mean) * rs); o0.w = f2b((a.w - mean) * rs);
    o1.x = f2b((b.x - mean) * rs); o1.y = f2b((b.y - mean) * rs);
    o1.z = f2b((b.z - mean) * rs); o1.w = f2b((b.w - mean) * rs);
    u16* op = out + (size_t)row * DMODEL + l * 8;
    *reinterpret_cast<ushort4*>(op) = o0;
    *reinterpret_cast<ushort4*>(op + 4) = o1;
}

// ---------------------------------------------------------------------------
// GEMM v8: C[M,N] = A[M,K] @ W[N,K]^T, 2-phase double-buffered (T3 minimum):
// issue next K-tile's global_load_lds BEFORE computing current; one
// vmcnt(0)+barrier per tile. K/64 must be even (all our K are 512/2048).
// OUTMODE: 0 = bf16 row-major, 1 = fp32 row-major,
//          3 = fused QKV: cols <1024 -> qk buffer [M][1024]; cols >=1024 ->
//              V4 interleaved store (B, S/4, 512, 4) (block-uniform on n0).
// ---------------------------------------------------------------------------
template <bool RELU, bool RESID, int OUTMODE>
__global__ __launch_bounds__(256, 2) void gemm_nt(
    const u16* __restrict__ A, const u16* __restrict__ W,
    const float* __restrict__ bias, const float* __restrict__ resid,
    void* __restrict__ Cout, void* __restrict__ Cout2, int N, int K) {
    __shared__ u16 Als[2][128 * 64];
    __shared__ u16 Bls[2][128 * 64];
    const int tid = threadIdx.x;
    const int l = tid & 63, w = tid >> 6;
    const int m0 = blockIdx.y * 128;
    const int n0 = blockIdx.x * 128;
    const int wr = (w >> 1) * 64, wc = (w & 1) * 64;
    const int lhi = l >> 4, l15 = l & 15, l7 = l & 7;

    f32x4 acc[4][4] = {};

    const int srow = l >> 3;
    const int scol = ((l & 7) * 8) ^ (srow << 3);

    auto stage = [&](int buf, int kt) {
#pragma unroll
        for (int i = 0; i < 4; ++i) {
            int cc = w * 4 + i;
            int grow = cc * 8 + srow;
            gload_lds16(&A[(size_t)(m0 + grow) * K + kt + scol],
                        &Als[buf][cc * 512]);
            gload_lds16(&W[(size_t)(n0 + grow) * K + kt + scol],
                        &Bls[buf][cc * 512]);
        }
    };

    auto compute = [&](int buf) {
#pragma unroll
        for (int kk = 0; kk < 2; ++kk) {
            const int koff = (kk * 32 + lhi * 8) ^ (l7 << 3);
            bf16x8 af[4], bfr[4];
#pragma unroll
            for (int m = 0; m < 4; ++m)
                af[m] = *reinterpret_cast<const bf16x8*>(
                    &Als[buf][(wr + m * 16 + l15) * 64 + koff]);
#pragma unroll
            for (int n = 0; n < 4; ++n)
                bfr[n] = *reinterpret_cast<const bf16x8*>(
                    &Bls[buf][(wc + n * 16 + l15) * 64 + koff]);
#pragma unroll
            for (int m = 0; m < 4; ++m)
#pragma unroll
                for (int n = 0; n < 4; ++n)
                    acc[m][n] = __builtin_amdgcn_mfma_f32_16x16x32_bf16(
                        af[m], bfr[n], acc[m][n], 0, 0, 0);
        }
    };

    stage(0, 0);
    asm volatile("s_waitcnt vmcnt(0)" ::: "memory");
    __builtin_amdgcn_s_barrier();

    for (int kt = 0; kt < K; kt += 128) {
        if (kt + 64 < K) stage(1, kt + 64);
        __builtin_amdgcn_sched_barrier(0);
        compute(0);
        asm volatile("s_waitcnt vmcnt(0)" ::: "memory");
        __builtin_amdgcn_s_barrier();
        if (kt + 128 < K) stage(0, kt + 128);
        __builtin_amdgcn_sched_barrier(0);
        compute(1);
        asm volatile("s_waitcnt vmcnt(0)" ::: "memory");
        __builtin_amdgcn_s_barrier();
    }

    int colg[4];
    float bv[4];
#pragma unroll
    for (int cn = 0; cn < 4; ++cn) {
        colg[cn] = n0 + wc + cn * 16 + l15;
        bv[cn] = bias[colg[cn]];
    }
#pragma unroll
    for (int am = 0; am < 4; ++am) {
        int rowg = m0 + wr + am * 16 + 4 * lhi;
#pragma unroll
        for (int cn = 0; cn < 4; ++cn) {
            float v[4];
#pragma unroll
            for (int r = 0; r < 4; ++r) {
                float t = acc[am][cn][r] + bv[cn];
                if constexpr (RELU) t = fmaxf(t, 0.f);
                if constexpr (RESID)
                    t += resid[(size_t)(rowg + r) * N + colg[cn]];
                v[r] = t;
            }
            if constexpr (OUTMODE == 0) {
                u16* o = (u16*)Cout;
#pragma unroll
                for (int r = 0; r < 4; ++r)
                    o[(size_t)(rowg + r) * N + colg[cn]] = f2b(v[r]);
            } else if constexpr (OUTMODE == 1) {
                float* o = (float*)Cout;
#pragma unroll
                for (int r = 0; r < 4; ++r)
                    o[(size_t)(rowg + r) * N + colg[cn]] = v[r];
            } else {
                // fused QKV: n0 is block-uniform
                if (n0 < 1024) {
                    u16* o = (u16*)Cout;  // qk buffer [M][1024]
#pragma unroll
                    for (int r = 0; r < 4; ++r)
                        o[(size_t)(rowg + r) * 1024 + colg[cn]] = f2b(v[r]);
                } else {
                    // V4: (B, S/4, 512, 4): elem = b*1048576 + (s>>2)*2048
                    //                              + d*4 + (s&3)
                    u16* o = (u16*)Cout2;
                    int bb = rowg >> 11, sloc = rowg & 2047;  // sloc % 4 == 0
                    int dg = colg[cn] - 1024;
                    ushort4 pk;
                    pk.x = f2b(v[0]); pk.y = f2b(v[1]);
                    pk.z = f2b(v[2]); pk.w = f2b(v[3]);
                    *reinterpret_cast<ushort4*>(
                        &o[(size_t)bb * 1048576 + (size_t)(sloc >> 2) * 2048 +
                           dg * 4]) = pk;
                }
            }
        }
    }
}

// ---------------------------------------------------------------------------
// Flash attention v8: identical to v7 but __launch_bounds__(256,3) —
// v7's (256,4) capped unified VGPR+AGPR at 128 and spilled (+14MB WRITE).
// K LDS (source-swizzled) + V4 LDS (conflict-free by layout), swapped QK^T
// (C1 pre-folded into w_q), clamped no-max softmax, PV 16x16x32, dbuf,
// t-loop unrolled x2 (compile-time buf). grid 1024 (XCD-swizzled).
// ---------------------------------------------------------------------------
__global__ __launch_bounds__(256, 3) void attn_fwd(
    const u16* __restrict__ qk, const u16* __restrict__ v4,
    const int* __restrict__ mask, u16* __restrict__ out) {
    __shared__ u16 Kls[2][64 * 64];
    __shared__ u16 Vls[2][64 * 64];  // [kg 0..15][d 0..63][key&3]
    const int tid = threadIdx.x;
    const int l = tid & 63, w = tid >> 6;
    const int lhi = l >> 4, l15 = l & 15;
    const int lb = (blockIdx.x & 7) * 128 + (blockIdx.x >> 3);  // XCD swizzle
    const int qt = lb & 15, bh = lb >> 4;
    const int b = bh >> 3, h = bh & 7;
    const int q0 = qt * 128 + w * 32;

    const u16* Qb = qk + (size_t)b * SEQ * 1024 + h * 64;
    const u16* Kb = Qb + 512;
    const u16* Vb4 = v4 + (size_t)b * 1048576 + h * 256;
    const int* Mb = mask + b * SEQ;

    const int srow = l >> 3;
    const int scol = ((l & 7) ^ srow) << 3;  // source-swizzled 16B chunk (K)

    bf16x8 qf[2][2];
#pragma unroll
    for (int g = 0; g < 2; ++g) {
        size_t qa = (size_t)(q0 + g * 16 + l15) * 1024 + lhi * 8;
        qf[g][0] = *reinterpret_cast<const bf16x8*>(&Qb[qa]);
        qf[g][1] = *reinterpret_cast<const bf16x8*>(&Qb[qa + 32]);
    }

    // whole-sequence mask check, once per block (fallback path kept general)
    int allone;
    {
        int acc = 1;
#pragma unroll
        for (int i = 0; i < 8; ++i) {
            int4 mm = *reinterpret_cast<const int4*>(&Mb[l * 32 + i * 4]);
            acc &= mm.x & mm.y & mm.z & mm.w;
        }
        allone = __all(acc == 1);
    }

    float lrun[2] = {0.f, 0.f};
    f32x4 oacc[2][4] = {};

    auto stage = [&](int buf, int kv) {
#pragma unroll
        for (int i = 0; i < 2; ++i) {
            int cc = w * 2 + i;
            int row = cc * 8 + srow;
            gload_lds16(&Kb[(size_t)(kv + row) * 1024 + scol], &Kls[buf][cc * 512]);
            gload_lds16(&Vb4[(size_t)((kv >> 2) + cc * 2 + (l >> 5)) * 2048 +
                             (l & 31) * 8],
                        &Vls[buf][cc * 512]);
        }
    };

    const int sw = (l15 & 7) << 3;

    // one KV tile: buf and pf are compile-time at each call site
    auto tile = [&](int buf, int kv, bool pf, int pbuf, int pkv) {
        if (pf) stage(pbuf, pkv);
        __builtin_amdgcn_sched_barrier(0);

        // --- QK^T (swapped): sc[g][ks][r] = S[key=kv+ks*16+4lhi+r][q=l15+16g]
        f32x4 sc[2][4];
        __builtin_amdgcn_s_setprio(1);
#pragma unroll
        for (int ks = 0; ks < 4; ++ks) {
            int krow = ks * 16 + l15;
            bf16x8 ka0 = *reinterpret_cast<const bf16x8*>(
                &Kls[buf][krow * 64 + ((lhi * 8) ^ sw)]);
            bf16x8 ka1 = *reinterpret_cast<const bf16x8*>(
                &Kls[buf][krow * 64 + ((32 + lhi * 8) ^ sw)]);
#pragma unroll
            for (int g = 0; g < 2; ++g) {
                f32x4 z = {};
                z = __builtin_amdgcn_mfma_f32_16x16x32_bf16(ka0, qf[g][0], z, 0, 0, 0);
                z = __builtin_amdgcn_mfma_f32_16x16x32_bf16(ka1, qf[g][1], z, 0, 0, 0);
                sc[g][ks] = z;
            }
        }
        __builtin_amdgcn_s_setprio(0);

        if (!allone) {
            int4 mm[4];
#pragma unroll
            for (int ks = 0; ks < 4; ++ks)
                mm[ks] = *reinterpret_cast<const int4*>(&Mb[kv + ks * 16 + 4 * lhi]);
#pragma unroll
            for (int ks = 0; ks < 4; ++ks) {
                if (mm[ks].x == 0) { sc[0][ks][0] = -3e38f; sc[1][ks][0] = -3e38f; }
                if (mm[ks].y == 0) { sc[0][ks][1] = -3e38f; sc[1][ks][1] = -3e38f; }
                if (mm[ks].z == 0) { sc[0][ks][2] = -3e38f; sc[1][ks][2] = -3e38f; }
                if (mm[ks].w == 0) { sc[0][ks][3] = -3e38f; sc[1][ks][3] = -3e38f; }
            }
        }

        // --- clamped no-max softmax: p = exp2(min(s, 30)) (C1 pre-folded).
        u32x4 pku[2][2];
#pragma unroll
        for (int g = 0; g < 2; ++g) {
            float ps = 0.f;
#pragma unroll
            for (int ks = 0; ks < 4; ++ks) {
                float p0 = ex2(fminf(sc[g][ks][0], 30.f));
                float p1 = ex2(fminf(sc[g][ks][1], 30.f));
                float p2 = ex2(fminf(sc[g][ks][2], 30.f));
                float p3 = ex2(fminf(sc[g][ks][3], 30.f));
                ps += (p0 + p1) + (p2 + p3);
                pku[g][ks >> 1][(ks & 1) * 2 + 0] = pack2(p0, p1);
                pku[g][ks >> 1][(ks & 1) * 2 + 1] = pack2(p2, p3);
            }
            ps += __shfl_xor(ps, 16, 64);
            ps += __shfl_xor(ps, 32, 64);
            lrun[g] += ps;
        }

        // --- PV at 16x16x32: slot j<4 -> key kp*32+4lhi+j; j>=4 -> +16.
        __builtin_amdgcn_s_setprio(1);
#pragma unroll
        for (int kp = 0; kp < 2; ++kp) {
#pragma unroll
            for (int dc = 0; dc < 4; ++dc) {
                int dl4 = (dc * 16 + l15) * 4;
                bf16x4 v0 = *reinterpret_cast<const bf16x4*>(
                    &Vls[buf][(kp * 8 + lhi) * 256 + dl4]);
                bf16x4 v1 = *reinterpret_cast<const bf16x4*>(
                    &Vls[buf][(kp * 8 + 4 + lhi) * 256 + dl4]);
                bf16x8 vb8;
                vb8[0] = v0[0]; vb8[1] = v0[1]; vb8[2] = v0[2]; vb8[3] = v0[3];
                vb8[4] = v1[0]; vb8[5] = v1[1]; vb8[6] = v1[2]; vb8[7] = v1[3];
#pragma unroll
                for (int g = 0; g < 2; ++g)
                    oacc[g][dc] = __builtin_amdgcn_mfma_f32_16x16x32_bf16(
                        __builtin_bit_cast(bf16x8, pku[g][kp]), vb8, oacc[g][dc],
                        0, 0, 0);
            }
        }
        __builtin_amdgcn_s_setprio(0);

        asm volatile("s_waitcnt vmcnt(0)" ::: "memory");
        __builtin_amdgcn_s_barrier();
    };

    stage(0, 0);
    asm volatile("s_waitcnt vmcnt(0)" ::: "memory");
    __builtin_amdgcn_s_barrier();

    for (int tt = 0; tt < 16; ++tt) {
        const int base = tt * 128;
        tile(0, base, true, 1, base + 64);
        tile(1, base + 64, tt < 15, 0, base + 128);
    }

    // --- epilogue: oacc row = q = 4lhi+r, col d = 16dc+l15
#pragma unroll
    for (int g = 0; g < 2; ++g) {
        float inv = 1.f / lrun[g];
        float invr[4];
#pragma unroll
        for (int r = 0; r < 4; ++r) invr[r] = __shfl(inv, 4 * lhi + r, 16);
#pragma unroll
        for (int r = 0; r < 4; ++r) {
            size_t rowa =
                ((size_t)b * SEQ + q0 + g * 16 + 4 * lhi + r) * DMODEL + h * 64;
#pragma unroll
            for (int dc = 0; dc < 4; ++dc)
                out[rowa + dc * 16 + l15] = f2b(oacc[g][dc][r] * invr[r]);
        }
    }
}

// ---------------------------------------------------------------------------
extern "C" void kernel_launch(void* const* d_in, const int* in_sizes, int n_in,
                              void* d_out, int out_size, void* d_ws,
                              size_t ws_size, hipStream_t stream) {
    const float* x = (const float*)d_in[0];
    const int* mask = (const int*)d_in[1];
    const float* w_q = (const float*)d_in[2];
    const float* b_q = (const float*)d_in[3];
    const float* w_k = (const float*)d_in[4];
    const float* b_k = (const float*)d_in[5];
    const float* w_v = (const float*)d_in[6];
    const float* b_v = (const float*)d_in[7];
    const float* w_o = (const float*)d_in[8];
    const float* b_o = (const float*)d_in[9];
    const float* w_1 = (const float*)d_in[10];
    const float* b_1 = (const float*)d_in[11];
    const float* w_2 = (const float*)d_in[12];
    const float* b_2 = (const float*)d_in[13];

    char* ws = (char*)d_ws;
    const size_t MB = 1024ull * 1024ull;
    u16* lnx = (u16*)(ws + 0);          // 16 MiB; reused as attn_out
    u16* qkb = (u16*)(ws + 16 * MB);    // 32 MiB [16,48): q|k interleaved rows
    u16* v4 = (u16*)(ws + 48 * MB);     // 16 MiB [48,64): (B,S/4,512,4)
    u16* lnx1 = (u16*)(ws + 16 * MB);   // after attn, qkb dead
    u16* hbuf = (u16*)(ws + 32 * MB);   // 64 MiB [32,96); qkb-hi, v4 dead
    u16* wqkv = (u16*)(ws + 96 * MB);   // [1536][512] (q|k|v rows contiguous)
    u16* wob = wqkv + 3 * 262144;
    u16* w1b = wqkv + 4 * 262144;
    u16* w2b = w1b + 1048576;
    float* bqkv = (float*)(w2b + 1048576);  // 1536 floats
    u16* attn_o = lnx;
    float* x1 = (float*)d_out;

    cast_weights<<<1536, 256, 0, stream>>>(
        w_q, w_k, w_v, w_o, w_1, w_2, wqkv, wqkv + 262144, wqkv + 2 * 262144,
        wob, w1b, w2b);
    concat_bias<<<6, 256, 0, stream>>>(b_q, b_k, b_v, bqkv);
    ln_rows<<<4096, 256, 0, stream>>>(x, lnx);

    dim3 g12(12, 128), g4(4, 128), g16(16, 128);
    gemm_nt<false, false, 3><<<g12, 256, 0, stream>>>(lnx, wqkv, bqkv, nullptr,
                                                      qkb, v4, 1536, 512);
    attn_fwd<<<1024, 256, 0, stream>>>(qkb, v4, mask, attn_o);
    gemm_nt<false, true, 1><<<g4, 256, 0, stream>>>(attn_o, wob, b_o, x, x1,
                                                    nullptr, 512, 512);
    ln_rows<<<4096, 256, 0, stream>>>(x1, lnx1);
    gemm_nt<true, false, 0><<<g16, 256, 0, stream>>>(lnx1, w1b, b_1, nullptr,
                                                     hbuf, nullptr, 2048, 512);
    gemm_nt<false, true, 1><<<g4, 256, 0, stream>>>(hbuf, w2b, b_2, x1,
                                                    (float*)d_out, nullptr,
                                                    512, 2048);
}

// Round 9
// 269.571 us; speedup vs baseline: 1.0756x; 1.0481x over previous
//
#include <hip/hip_runtime.h>
#include <hip/hip_bf16.h>

typedef unsigned short u16;
typedef __bf16 bf16x8 __attribute__((ext_vector_type(8)));
typedef unsigned int u32x4 __attribute__((ext_vector_type(4)));
typedef float f32x4 __attribute__((ext_vector_type(4)));

#define SEQ 2048
#define DMODEL 512
#define NHEAD 8
#define DFF 2048
#define NBATCH 8
#define MROWS (NBATCH * SEQ)

// 0.125 * log2(e): folded into w_q/b_q so attn softmax is exp2(s) directly
#define C1_FOLD 0.18033688f

__device__ __forceinline__ u16 f2b(float f) {
    __hip_bfloat16 h = __float2bfloat16(f);
    u16 u;
    __builtin_memcpy(&u, &h, 2);
    return u;
}

__device__ __forceinline__ unsigned int pack2(float a, float b) {
    float2 f{a, b};
    __hip_bfloat162 h = __float22bfloat162_rn(f);
    unsigned int u;
    __builtin_memcpy(&u, &h, 4);
    return u;
}

__device__ __forceinline__ float ex2(float x) {
#if __has_builtin(__builtin_amdgcn_exp2f)
    return __builtin_amdgcn_exp2f(x);
#else
    return exp2f(x);
#endif
}

// async global->LDS, 16B per lane. LDS dest must be wave-uniform base; lane i
// lands at base + i*16.
__device__ __forceinline__ void gload_lds16(const void* g, void* lds) {
    auto* gp = reinterpret_cast<const __attribute__((address_space(1))) unsigned int*>(
        reinterpret_cast<uintptr_t>(g));
    auto* lp = reinterpret_cast<__attribute__((address_space(3))) unsigned int*>(
        reinterpret_cast<uintptr_t>(lds));
    __builtin_amdgcn_global_load_lds(gp, lp, 16, 0, 0);
}

// ---------------------------------------------------------------------------
// Weight cast fp32 -> bf16 (6 matrices in one launch). w_q scaled by C1.
// ---------------------------------------------------------------------------
__global__ __launch_bounds__(256) void cast_weights(
    const float* __restrict__ w0, const float* __restrict__ w1,
    const float* __restrict__ w2, const float* __restrict__ w3,
    const float* __restrict__ w4, const float* __restrict__ w5,
    u16* __restrict__ d0, u16* __restrict__ d1, u16* __restrict__ d2,
    u16* __restrict__ d3, u16* __restrict__ d4, u16* __restrict__ d5) {
    int blk = blockIdx.x;
    const float* s;
    u16* d;
    int base;
    float sc = 1.0f;
    if (blk < 512) {
        int seg = blk >> 7, lb = blk & 127;
        s = seg == 0 ? w0 : seg == 1 ? w1 : seg == 2 ? w2 : w3;
        d = seg == 0 ? d0 : seg == 1 ? d1 : seg == 2 ? d2 : d3;
        base = lb * 2048;
        if (seg == 0) sc = C1_FOLD;
    } else if (blk < 1024) {
        s = w4; d = d4; base = (blk - 512) * 2048;
    } else {
        s = w5; d = d5; base = (blk - 1024) * 2048;
    }
    int i = base + threadIdx.x * 8;
    float4 a = *reinterpret_cast<const float4*>(s + i);
    float4 b = *reinterpret_cast<const float4*>(s + i + 4);
    ushort4 oa, ob;
    oa.x = f2b(a.x * sc); oa.y = f2b(a.y * sc);
    oa.z = f2b(a.z * sc); oa.w = f2b(a.w * sc);
    ob.x = f2b(b.x * sc); ob.y = f2b(b.y * sc);
    ob.z = f2b(b.z * sc); ob.w = f2b(b.w * sc);
    *reinterpret_cast<ushort4*>(d + i) = oa;
    *reinterpret_cast<ushort4*>(d + i + 4) = ob;
}

// concat b_q*C1 | b_k | b_v -> bqkv[1536]
__global__ __launch_bounds__(256) void concat_bias(const float* __restrict__ bq,
                                                   const float* __restrict__ bk,
                                                   const float* __restrict__ bv,
                                                   float* __restrict__ dst) {
    int i = blockIdx.x * 256 + threadIdx.x;
    float v = i < 512 ? bq[i] * C1_FOLD : (i < 1024 ? bk[i - 512] : bv[i - 1024]);
    dst[i] = v;
}

// ---------------------------------------------------------------------------
// LayerNorm (unbiased var, ddof=1), fp32 in -> bf16 out. 1 wave / 512-row.
// ---------------------------------------------------------------------------
__global__ __launch_bounds__(256) void ln_rows(const float* __restrict__ x,
                                               u16* __restrict__ out) {
    int row = blockIdx.x * 4 + (threadIdx.x >> 6);
    int l = threadIdx.x & 63;
    const float* xr = x + (size_t)row * DMODEL + l * 8;
    float4 a = *reinterpret_cast<const float4*>(xr);
    float4 b = *reinterpret_cast<const float4*>(xr + 4);
    float s = a.x + a.y + a.z + a.w + b.x + b.y + b.z + b.w;
    float q = a.x * a.x + a.y * a.y + a.z * a.z + a.w * a.w +
              b.x * b.x + b.y * b.y + b.z * b.z + b.w * b.w;
#pragma unroll
    for (int d = 32; d >= 1; d >>= 1) {
        s += __shfl_xor(s, d, 64);
        q += __shfl_xor(q, d, 64);
    }
    float mean = s * (1.f / 512.f);
    float var = (q - 512.f * mean * mean) * (1.f / 511.f);
    float rs = rsqrtf(var + 1e-6f);
    ushort4 o0, o1;
    o0.x = f2b((a.x - mean) * rs); o0.y = f2b((a.y - mean) * rs);
    o0.z = f2b((a.z - mean) * rs); o0.w = f2b((a.w - mean) * rs);
    o1.x = f2b((b.x - mean) * rs); o1.y = f2b((b.y - mean) * rs);
    o1.z = f2b((b.z - mean) * rs); o1.w = f2b((b.w - mean) * rs);
    u16* op = out + (size_t)row * DMODEL + l * 8;
    *reinterpret_cast<ushort4*>(op) = o0;
    *reinterpret_cast<ushort4*>(op + 4) = o1;
}

// ---------------------------------------------------------------------------
// GEMM: C[M,N] = A[M,K] @ W[N,K]^T, 2-phase double-buffered.
// OUTMODE: 0 = bf16 row-major, 1 = fp32 row-major,
//          3 = fused QKV: cols <1024 -> qk buffer [M][1024]; cols >=1024 ->
//              V8 store (B, S/32, 4, 512, 8), key = kk*32 + hb*16 + s*4 + j.
// ---------------------------------------------------------------------------
template <bool RELU, bool RESID, int OUTMODE>
__global__ __launch_bounds__(256, 2) void gemm_nt(
    const u16* __restrict__ A, const u16* __restrict__ W,
    const float* __restrict__ bias, const float* __restrict__ resid,
    void* __restrict__ Cout, void* __restrict__ Cout2, int N, int K) {
    __shared__ u16 Als[2][128 * 64];
    __shared__ u16 Bls[2][128 * 64];
    const int tid = threadIdx.x;
    const int l = tid & 63, w = tid >> 6;
    const int m0 = blockIdx.y * 128;
    const int n0 = blockIdx.x * 128;
    const int wr = (w >> 1) * 64, wc = (w & 1) * 64;
    const int lhi = l >> 4, l15 = l & 15, l7 = l & 7;

    f32x4 acc[4][4] = {};

    const int srow = l >> 3;
    const int scol = ((l & 7) * 8) ^ (srow << 3);

    auto stage = [&](int buf, int kt) {
#pragma unroll
        for (int i = 0; i < 4; ++i) {
            int cc = w * 4 + i;
            int grow = cc * 8 + srow;
            gload_lds16(&A[(size_t)(m0 + grow) * K + kt + scol],
                        &Als[buf][cc * 512]);
            gload_lds16(&W[(size_t)(n0 + grow) * K + kt + scol],
                        &Bls[buf][cc * 512]);
        }
    };

    auto compute = [&](int buf) {
#pragma unroll
        for (int kk = 0; kk < 2; ++kk) {
            const int koff = (kk * 32 + lhi * 8) ^ (l7 << 3);
            bf16x8 af[4], bfr[4];
#pragma unroll
            for (int m = 0; m < 4; ++m)
                af[m] = *reinterpret_cast<const bf16x8*>(
                    &Als[buf][(wr + m * 16 + l15) * 64 + koff]);
#pragma unroll
            for (int n = 0; n < 4; ++n)
                bfr[n] = *reinterpret_cast<const bf16x8*>(
                    &Bls[buf][(wc + n * 16 + l15) * 64 + koff]);
#pragma unroll
            for (int m = 0; m < 4; ++m)
#pragma unroll
                for (int n = 0; n < 4; ++n)
                    acc[m][n] = __builtin_amdgcn_mfma_f32_16x16x32_bf16(
                        af[m], bfr[n], acc[m][n], 0, 0, 0);
        }
    };

    stage(0, 0);
    asm volatile("s_waitcnt vmcnt(0)" ::: "memory");
    __builtin_amdgcn_s_barrier();

    for (int kt = 0; kt < K; kt += 128) {
        if (kt + 64 < K) stage(1, kt + 64);
        __builtin_amdgcn_sched_barrier(0);
        compute(0);
        asm volatile("s_waitcnt vmcnt(0)" ::: "memory");
        __builtin_amdgcn_s_barrier();
        if (kt + 128 < K) stage(0, kt + 128);
        __builtin_amdgcn_sched_barrier(0);
        compute(1);
        asm volatile("s_waitcnt vmcnt(0)" ::: "memory");
        __builtin_amdgcn_s_barrier();
    }

    int colg[4];
    float bv[4];
#pragma unroll
    for (int cn = 0; cn < 4; ++cn) {
        colg[cn] = n0 + wc + cn * 16 + l15;
        bv[cn] = bias[colg[cn]];
    }
#pragma unroll
    for (int am = 0; am < 4; ++am) {
        int rowg = m0 + wr + am * 16 + 4 * lhi;
#pragma unroll
        for (int cn = 0; cn < 4; ++cn) {
            float v[4];
#pragma unroll
            for (int r = 0; r < 4; ++r) {
                float t = acc[am][cn][r] + bv[cn];
                if constexpr (RELU) t = fmaxf(t, 0.f);
                if constexpr (RESID)
                    t += resid[(size_t)(rowg + r) * N + colg[cn]];
                v[r] = t;
            }
            if constexpr (OUTMODE == 0) {
                u16* o = (u16*)Cout;
#pragma unroll
                for (int r = 0; r < 4; ++r)
                    o[(size_t)(rowg + r) * N + colg[cn]] = f2b(v[r]);
            } else if constexpr (OUTMODE == 1) {
                float* o = (float*)Cout;
#pragma unroll
                for (int r = 0; r < 4; ++r)
                    o[(size_t)(rowg + r) * N + colg[cn]] = v[r];
            } else {
                // fused QKV: n0 is block-uniform
                if (n0 < 1024) {
                    u16* o = (u16*)Cout;  // qk buffer [M][1024]
#pragma unroll
                    for (int r = 0; r < 4; ++r)
                        o[(size_t)(rowg + r) * 1024 + colg[cn]] = f2b(v[r]);
                } else {
                    // V8 (B, S/32, 4, 512, 8): 4 consecutive keys share
                    // (kk, hb, s), j = 0..3 -> one contiguous 8B store
                    u16* o = (u16*)Cout2;
                    int bb = rowg >> 11, sloc = rowg & 2047;  // sloc % 4 == 0
                    int dg = colg[cn] - 1024;
                    int kk = sloc >> 5, hb = (sloc >> 4) & 1, ss = (sloc >> 2) & 3;
                    ushort4 pk;
                    pk.x = f2b(v[0]); pk.y = f2b(v[1]);
                    pk.z = f2b(v[2]); pk.w = f2b(v[3]);
                    *reinterpret_cast<ushort4*>(
                        &o[(size_t)(bb * 64 + kk) * 16384 + ss * 4096 + dg * 8 +
                           hb * 4]) = pk;
                }
            }
        }
    }
}

// ---------------------------------------------------------------------------
// Flash attention v9: K LDS (source-swizzled) + V8 LDS (B-frag = one b128,
// conflict-free, zero assembly movs), swapped QK^T (C1 pre-folded), clamped
// no-max softmax, PV 16x16x32, row-sum via MFMA against ones (no shuffle
// reduction). Double-buffered, t-loop unrolled x2 (compile-time buf).
// qk: (B,S,1024) bf16; v8: (B,S/32,4,512,8) bf16.
// Block = 128 q x (b,h), 4 waves; grid 1024 (XCD-swizzled).
// ---------------------------------------------------------------------------
__global__ __launch_bounds__(256, 3) void attn_fwd(
    const u16* __restrict__ qk, const u16* __restrict__ v8,
    const int* __restrict__ mask, u16* __restrict__ out) {
    __shared__ u16 Kls[2][64 * 64];
    __shared__ u16 Vls[2][8 * 512];  // [cc = kkl*4 + s][d_loc*8 + hb*4 + j]
    const int tid = threadIdx.x;
    const int l = tid & 63, w = tid >> 6;
    const int lhi = l >> 4, l15 = l & 15;
    const int lb = (blockIdx.x & 7) * 128 + (blockIdx.x >> 3);  // XCD swizzle
    const int qt = lb & 15, bh = lb >> 4;
    const int b = bh >> 3, h = bh & 7;
    const int q0 = qt * 128 + w * 32;

    const u16* Qb = qk + (size_t)b * SEQ * 1024 + h * 64;
    const u16* Kb = Qb + 512;
    const u16* Vb8 = v8 + (size_t)b * 1048576 + h * 512;
    const int* Mb = mask + b * SEQ;

    const int srow = l >> 3;
    const int scol = ((l & 7) ^ srow) << 3;  // source-swizzled 16B chunk (K)

    bf16x8 qf[2][2];
#pragma unroll
    for (int g = 0; g < 2; ++g) {
        size_t qa = (size_t)(q0 + g * 16 + l15) * 1024 + lhi * 8;
        qf[g][0] = *reinterpret_cast<const bf16x8*>(&Qb[qa]);
        qf[g][1] = *reinterpret_cast<const bf16x8*>(&Qb[qa + 32]);
    }

    bf16x8 ones8;
#pragma unroll
    for (int i = 0; i < 8; ++i) ones8[i] = (__bf16)1.0f;

    // whole-sequence mask check, once per block (fallback path kept general)
    int allone;
    {
        int acc = 1;
#pragma unroll
        for (int i = 0; i < 8; ++i) {
            int4 mm = *reinterpret_cast<const int4*>(&Mb[l * 32 + i * 4]);
            acc &= mm.x & mm.y & mm.z & mm.w;
        }
        allone = __all(acc == 1);
    }

    f32x4 oacc[2][4] = {};
    f32x4 osum[2] = {};  // row-sums of P, accumulated on the matrix pipe

    auto stage = [&](int buf, int kv) {
#pragma unroll
        for (int i = 0; i < 2; ++i) {
            int cc = w * 2 + i;
            int row = cc * 8 + srow;
            gload_lds16(&Kb[(size_t)(kv + row) * 1024 + scol], &Kls[buf][cc * 512]);
            gload_lds16(&Vb8[(size_t)((kv >> 5) + (cc >> 2)) * 16384 +
                             (cc & 3) * 4096 + l * 8],
                        &Vls[buf][cc * 512]);
        }
    };

    const int sw = (l15 & 7) << 3;

    // one KV tile: buf and pf are compile-time at each call site
    auto tile = [&](int buf, int kv, bool pf, int pbuf, int pkv) {
        if (pf) stage(pbuf, pkv);
        __builtin_amdgcn_sched_barrier(0);

        // --- QK^T (swapped): sc[g][ks][r] = S[key=kv+ks*16+4lhi+r][q=l15+16g]
        f32x4 sc[2][4];
        __builtin_amdgcn_s_setprio(1);
#pragma unroll
        for (int ks = 0; ks < 4; ++ks) {
            int krow = ks * 16 + l15;
            bf16x8 ka0 = *reinterpret_cast<const bf16x8*>(
                &Kls[buf][krow * 64 + ((lhi * 8) ^ sw)]);
            bf16x8 ka1 = *reinterpret_cast<const bf16x8*>(
                &Kls[buf][krow * 64 + ((32 + lhi * 8) ^ sw)]);
#pragma unroll
            for (int g = 0; g < 2; ++g) {
                f32x4 z = {};
                z = __builtin_amdgcn_mfma_f32_16x16x32_bf16(ka0, qf[g][0], z, 0, 0, 0);
                z = __builtin_amdgcn_mfma_f32_16x16x32_bf16(ka1, qf[g][1], z, 0, 0, 0);
                sc[g][ks] = z;
            }
        }
        __builtin_amdgcn_s_setprio(0);

        if (!allone) {
            int4 mm[4];
#pragma unroll
            for (int ks = 0; ks < 4; ++ks)
                mm[ks] = *reinterpret_cast<const int4*>(&Mb[kv + ks * 16 + 4 * lhi]);
#pragma unroll
            for (int ks = 0; ks < 4; ++ks) {
                if (mm[ks].x == 0) { sc[0][ks][0] = -3e38f; sc[1][ks][0] = -3e38f; }
                if (mm[ks].y == 0) { sc[0][ks][1] = -3e38f; sc[1][ks][1] = -3e38f; }
                if (mm[ks].z == 0) { sc[0][ks][2] = -3e38f; sc[1][ks][2] = -3e38f; }
                if (mm[ks].w == 0) { sc[0][ks][3] = -3e38f; sc[1][ks][3] = -3e38f; }
            }
        }

        // --- clamped no-max softmax: p = exp2(min(s, 30)) (C1 pre-folded).
        // A-frag slots: j<4 -> key kp*32+4lhi+j; j>=4 -> kp*32+16+4lhi+(j-4).
        u32x4 pku[2][2];
#pragma unroll
        for (int g = 0; g < 2; ++g) {
#pragma unroll
            for (int ks = 0; ks < 4; ++ks) {
                float p0 = ex2(fminf(sc[g][ks][0], 30.f));
                float p1 = ex2(fminf(sc[g][ks][1], 30.f));
                float p2 = ex2(fminf(sc[g][ks][2], 30.f));
                float p3 = ex2(fminf(sc[g][ks][3], 30.f));
                pku[g][ks >> 1][(ks & 1) * 2 + 0] = pack2(p0, p1);
                pku[g][ks >> 1][(ks & 1) * 2 + 1] = pack2(p2, p3);
            }
        }

        // --- PV at 16x16x32: B-frag = one contiguous b128 from V8 LDS;
        // row-sum MFMA with ones B gives denominator in oacc row layout.
        __builtin_amdgcn_s_setprio(1);
#pragma unroll
        for (int kp = 0; kp < 2; ++kp) {
#pragma unroll
            for (int dc = 0; dc < 4; ++dc) {
                bf16x8 vb8 = *reinterpret_cast<const bf16x8*>(
                    &Vls[buf][(kp * 4 + lhi) * 512 + (dc * 16 + l15) * 8]);
#pragma unroll
                for (int g = 0; g < 2; ++g)
                    oacc[g][dc] = __builtin_amdgcn_mfma_f32_16x16x32_bf16(
                        __builtin_bit_cast(bf16x8, pku[g][kp]), vb8, oacc[g][dc],
                        0, 0, 0);
            }
#pragma unroll
            for (int g = 0; g < 2; ++g)
                osum[g] = __builtin_amdgcn_mfma_f32_16x16x32_bf16(
                    __builtin_bit_cast(bf16x8, pku[g][kp]), ones8, osum[g],
                    0, 0, 0);
        }
        __builtin_amdgcn_s_setprio(0);

        asm volatile("s_waitcnt vmcnt(0)" ::: "memory");
        __builtin_amdgcn_s_barrier();
    };

    stage(0, 0);
    asm volatile("s_waitcnt vmcnt(0)" ::: "memory");
    __builtin_amdgcn_s_barrier();

    for (int tt = 0; tt < 16; ++tt) {
        const int base = tt * 128;
        tile(0, base, true, 1, base + 64);
        tile(1, base + 64, tt < 15, 0, base + 128);
    }

    // --- epilogue: oacc row = q = 4lhi+r, col d = 16dc+l15; osum[g][r] is
    // the matching row's denominator (no cross-lane shuffle needed).
#pragma unroll
    for (int g = 0; g < 2; ++g) {
#pragma unroll
        for (int r = 0; r < 4; ++r) {
            float inv = 1.f / osum[g][r];
            size_t rowa =
                ((size_t)b * SEQ + q0 + g * 16 + 4 * lhi + r) * DMODEL + h * 64;
#pragma unroll
            for (int dc = 0; dc < 4; ++dc)
                out[rowa + dc * 16 + l15] = f2b(oacc[g][dc][r] * inv);
        }
    }
}

// ---------------------------------------------------------------------------
extern "C" void kernel_launch(void* const* d_in, const int* in_sizes, int n_in,
                              void* d_out, int out_size, void* d_ws,
                              size_t ws_size, hipStream_t stream) {
    const float* x = (const float*)d_in[0];
    const int* mask = (const int*)d_in[1];
    const float* w_q = (const float*)d_in[2];
    const float* b_q = (const float*)d_in[3];
    const float* w_k = (const float*)d_in[4];
    const float* b_k = (const float*)d_in[5];
    const float* w_v = (const float*)d_in[6];
    const float* b_v = (const float*)d_in[7];
    const float* w_o = (const float*)d_in[8];
    const float* b_o = (const float*)d_in[9];
    const float* w_1 = (const float*)d_in[10];
    const float* b_1 = (const float*)d_in[11];
    const float* w_2 = (const float*)d_in[12];
    const float* b_2 = (const float*)d_in[13];

    char* ws = (char*)d_ws;
    const size_t MB = 1024ull * 1024ull;
    u16* lnx = (u16*)(ws + 0);          // 16 MiB; reused as attn_out
    u16* qkb = (u16*)(ws + 16 * MB);    // 32 MiB [16,48): q|k interleaved rows
    u16* v8 = (u16*)(ws + 48 * MB);     // 16 MiB [48,64): (B,S/32,4,512,8)
    u16* lnx1 = (u16*)(ws + 16 * MB);   // after attn, qkb dead
    u16* hbuf = (u16*)(ws + 32 * MB);   // 64 MiB [32,96); qkb-hi, v8 dead
    u16* wqkv = (u16*)(ws + 96 * MB);   // [1536][512] (q|k|v rows contiguous)
    u16* wob = wqkv + 3 * 262144;
    u16* w1b = wqkv + 4 * 262144;
    u16* w2b = w1b + 1048576;
    float* bqkv = (float*)(w2b + 1048576);  // 1536 floats
    u16* attn_o = lnx;
    float* x1 = (float*)d_out;

    cast_weights<<<1536, 256, 0, stream>>>(
        w_q, w_k, w_v, w_o, w_1, w_2, wqkv, wqkv + 262144, wqkv + 2 * 262144,
        wob, w1b, w2b);
    concat_bias<<<6, 256, 0, stream>>>(b_q, b_k, b_v, bqkv);
    ln_rows<<<4096, 256, 0, stream>>>(x, lnx);

    dim3 g12(12, 128), g4(4, 128), g16(16, 128);
    gemm_nt<false, false, 3><<<g12, 256, 0, stream>>>(lnx, wqkv, bqkv, nullptr,
                                                      qkb, v8, 1536, 512);
    attn_fwd<<<1024, 256, 0, stream>>>(qkb, v8, mask, attn_o);
    gemm_nt<false, true, 1><<<g4, 256, 0, stream>>>(attn_o, wob, b_o, x, x1,
                                                    nullptr, 512, 512);
    ln_rows<<<4096, 256, 0, stream>>>(x1, lnx1);
    gemm_nt<true, false, 0><<<g16, 256, 0, stream>>>(lnx1, w1b, b_1, nullptr,
                                                     hbuf, nullptr, 2048, 512);
    gemm_nt<false, true, 1><<<g4, 256, 0, stream>>>(hbuf, w2b, b_2, x1,
                                                    (float*)d_out, nullptr,
                                                    512, 2048);
}